// Round 1
// 248.174 us; speedup vs baseline: 1.0423x; 1.0423x over previous
//
#include <hip/hip_runtime.h>
#include <hip/hip_bf16.h>

// Pseudo-3D DCN: B=2, C=32, T=8, H=W=192, K=9 (3x3, pad 1), groups=deform_groups=T.
// Round 4: owner-computes sampling params + plane-major halo for 3 blocks/CU.
//   - per tap k, each lane computes weights/addresses ONCE for its own pixel
//     (was 4x redundant across quads) and shares via a wave-private LDS param
//     buffer (no barrier needed: producers/consumers are the same wave).
//   - halo stored plane-major: 4 planes x 17x41 uint4 (64 B/pixel, plane
//     stride 697*16B == 4 dwords mod 32 -> same 2-way-free bank pattern as the
//     old 80B padding, but LDS drops 55.8KB -> 50.75KB incl. params -> 3 blk/CU.
//   - B-frags + offsets loaded per-tap (offsets pipelined 1 tap ahead) to fit
//     the (256,3) VGPR budget.

#define CIN   32
#define COUT  32
#define TT    8
#define HH    192
#define WW    192
#define KK    9
#define HWSZ  (HH * WW)        // 36864
#define PLANE (TT * HWSZ)      // 294912

#define TILE_W 32
#define TILE_H 8
#define HALO   4
#define HROWS  (TILE_H + 2 * HALO + 1)   // 17
#define HCOLS  (TILE_W + 2 * HALO + 1)   // 41
#define HPLANE (HROWS * HCOLS)           // 697
#define HPLANE_B (HPLANE * 16)           // 11152 bytes per channel-part plane
#define HROW_B  (HCOLS * 16)             // 656 bytes per halo row

typedef __attribute__((ext_vector_type(8))) short short8;
typedef __attribute__((ext_vector_type(4))) float f32x4;

union U4S8 { uint4 u; short8 s; };

__device__ __forceinline__ float bl_lo(uint u) { return __uint_as_float(u << 16); }
__device__ __forceinline__ float bl_hi(uint u) { return __uint_as_float(u & 0xffff0000u); }

__device__ __forceinline__ uint pk_bf16(float lo, float hi) {
    float2 p; p.x = lo; p.y = hi;
    __hip_bfloat162 b = __float22bfloat162_rn(p);
    union { __hip_bfloat162 b; uint u; } cv; cv.b = b;
    return cv.u;
}

// bilinear-combine one dword (2 channels) from 4 corners, pack to bf16x2
__device__ __forceinline__ uint blerp_pack(uint a, uint b, uint c, uint d,
                                           float w00, float w01, float w10, float w11) {
    float lo = w00 * bl_lo(a) + w01 * bl_lo(b) + w10 * bl_lo(c) + w11 * bl_lo(d);
    float hi = w00 * bl_hi(a) + w01 * bl_hi(b) + w10 * bl_hi(c) + w11 * bl_hi(d);
    return pk_bf16(lo, hi);
}

// ---------------------------------------------------------------------------
// feat f32 [B,C,T,H,W] -> tf bf16 [B,T,H,W,C] (stored as uint = 2 channels)
// 256-pixel blocks: global reads are 1 KB per wave-instruction.
// ---------------------------------------------------------------------------
__global__ __launch_bounds__(256) void transpose_bf16_kernel(
    const float* __restrict__ feat, uint* __restrict__ tf)
{
    __shared__ float tile[CIN][257];
    const int p0 = blockIdx.x * 256;
    const int t  = blockIdx.y;
    const int b  = blockIdx.z;

    const float* src = feat + (size_t)b * CIN * PLANE + (size_t)t * HWSZ + p0;
    #pragma unroll
    for (int c = 0; c < CIN; ++c)
        tile[c][threadIdx.x] = src[(size_t)c * PLANE + threadIdx.x];
    __syncthreads();

    uint* dst = tf + ((size_t)(b * TT + t) * HWSZ + p0) * (CIN / 2);
    #pragma unroll
    for (int it = 0; it < 16; ++it) {
        int i  = it * 256 + threadIdx.x;   // 0..4095
        int p  = i >> 4, c2 = i & 15;
        dst[p * 16 + c2] = pk_bf16(tile[2 * c2][p], tile[2 * c2 + 1][p]);
    }
}

// ---------------------------------------------------------------------------
// weight f32 [T][o=32][c=32][k=9] -> wfrag bf16 [t][k][n][lane][j]
//   B-frag element: B[k_dim = (lane>>4)*8 + j][n = ntile*16 + (lane&15)]
// ---------------------------------------------------------------------------
__global__ __launch_bounds__(256) void wprep_kernel(
    const float* __restrict__ wt, ushort* __restrict__ wfrag)
{
    int idx = blockIdx.x * 256 + threadIdx.x;
    if (idx >= TT * KK * 2 * 64 * 8) return;
    int t  = idx / (KK * 1024);
    int f  = idx % (KK * 1024);
    int k  = f >> 10;
    int r2 = f & 1023;
    int n    = r2 >> 9;
    int lane = (r2 >> 3) & 63;
    int j    = r2 & 7;
    int o = n * 16 + (lane & 15);
    int c = (lane >> 4) * 8 + j;
    float v = wt[(((size_t)t * COUT + o) * CIN + c) * KK + k];
    __hip_bfloat16 hb = __float2bfloat16(v);
    union { __hip_bfloat16 b; ushort u; } cv; cv.b = hb;
    wfrag[idx] = cv.u;
}

// ---------------------------------------------------------------------------
// Main MFMA kernel. Block 256 thr = 4 waves. Tile 32x8 pixels.
// Wave wv owns rows h0+2wv, h0+2wv+1; 4 M-tiles of 16 pixels each.
// ---------------------------------------------------------------------------
__global__ __launch_bounds__(256, 3) void dcn_mfma_kernel(
    const uint* __restrict__ tf,        // bf16 channels-last [bt][pix][c/2]
    const float* __restrict__ offset,
    const ushort* __restrict__ wfrag,
    float* __restrict__ out)
{
    __shared__ uint4 halo4[4 * HPLANE];   // plane-major, 44608 B
    __shared__ f32x4 wts[256];            // 4096 B  (per-tap bilinear weights)
    __shared__ uint2 meta2[256];          // 2048 B  (packed addr / fallback coords)

    const int tid  = threadIdx.x;
    const int lane = tid & 63;
    const int wv   = tid >> 6;
    const int lane15 = lane & 15;
    const int quad   = lane >> 4;

    const int w0 = blockIdx.x * TILE_W;
    const int h0 = blockIdx.y * TILE_H;
    const int bt = blockIdx.z;
    const int t  = bt & (TT - 1);
    const int b  = bt >> 3;

    const int hlo = h0 - HALO, wlo = w0 - HALO;
    const int hhi = hlo + (HROWS - 1), whi = wlo + (HCOLS - 1);

    const uint4* tfs4 = (const uint4*)tf + (size_t)bt * HWSZ * 4;  // 4 uint4/pixel

    // ---- stage halo (edge-replicated) into LDS, plane-major ----
    #pragma unroll
    for (int it = 0; it < 11; ++it) {
        int idx = it * 256 + tid;
        if (idx < 4 * HPLANE) {
            int r    = idx / (HCOLS * 4);
            int rem  = idx - r * (HCOLS * 4);
            int pv   = rem >> 2;
            int part = rem & 3;
            int gy = min(max(hlo + r, 0), HH - 1);
            int gx = min(max(wlo + pv, 0), WW - 1);
            halo4[part * HPLANE + r * HCOLS + pv] = tfs4[(gy * WW + gx) * 4 + part];
        }
    }

    // ---- own pixel (producer role): lane owns one of the wave's 64 pixels ----
    const int prow = h0 + 2 * wv + (lane >> 5);
    const int pcol = w0 + (lane & 31);
    const int px_own = (2 * wv + (lane >> 5)) * 32 + (lane & 31);
    const float* offp = offset + (size_t)b * 2 * KK * PLANE + (size_t)t * HWSZ
                      + prow * WW + pcol;

    const uint4* wfp = (const uint4*)(wfrag + (size_t)t * KK * 2 * 64 * 8);

    f32x4 acc[4][2];
    #pragma unroll
    for (int i = 0; i < 4; ++i)
        #pragma unroll
        for (int n = 0; n < 2; ++n) {
            acc[i][n][0] = 0.f; acc[i][n][1] = 0.f;
            acc[i][n][2] = 0.f; acc[i][n][3] = 0.f;
        }

    // consumer-side param indices (same across taps)
    int pxc[4];
    #pragma unroll
    for (int i = 0; i < 4; ++i)
        pxc[i] = (2 * wv + (i >> 1)) * 32 + ((i & 1) << 4) + lane15;

    const uint qb = (uint)quad * HPLANE_B;
    const char* hbase = (const char*)halo4;

    __syncthreads();

    // software-pipelined offset loads (one tap ahead)
    float dy = offp[0];
    float dx = offp[(size_t)PLANE];

    #pragma unroll
    for (int k = 0; k < KK; ++k) {
        const int ky = k / 3 - 1;
        const int kx = k % 3 - 1;

        float dyn = 0.f, dxn = 0.f;
        if (k < KK - 1) {
            dyn = offp[(size_t)(2 * k + 2) * PLANE];
            dxn = offp[(size_t)(2 * k + 3) * PLANE];
        }

        // B-fragments for this tap (L1-hot: 9 KB shared by all waves of this t)
        U4S8 bf0, bf1;
        bf0.u = wfp[(k * 2 + 0) * 64 + lane];
        bf1.u = wfp[(k * 2 + 1) * 64 + lane];

        // ---- producer: sampling math ONCE per pixel (was 4x across quads) ----
        {
            const float ys = (float)(prow + ky) + dy;
            const float xs = (float)(pcol + kx) + dx;
            const float y0f = floorf(ys), x0f = floorf(xs);
            const float wy1 = ys - y0f,  wx1 = xs - x0f;
            const float wy0 = 1.f - wy1, wx0 = 1.f - wx1;

            const int y0 = (int)y0f, x0i = (int)x0f;
            const int y1 = y0 + 1,   x1 = x0i + 1;

            const float vy0 = (y0 >= 0 && y0 < HH) ? 1.f : 0.f;
            const float vy1 = (y1 >= 0 && y1 < HH) ? 1.f : 0.f;
            const float vx0 = (x0i >= 0 && x0i < WW) ? 1.f : 0.f;
            const float vx1 = (x1 >= 0 && x1 < WW) ? 1.f : 0.f;

            const int cy0 = min(max(y0, 0), HH - 1);
            const int cy1 = min(max(y1, 0), HH - 1);
            const int cx0 = min(max(x0i, 0), WW - 1);
            const int cx1 = min(max(x1, 0), WW - 1);

            f32x4 w4;
            w4[0] = wy0 * wx0 * vy0 * vx0;
            w4[1] = wy0 * wx1 * vy0 * vx1;
            w4[2] = wy1 * wx0 * vy1 * vx0;
            w4[3] = wy1 * wx1 * vy1 * vx1;

            const bool inH = (cy0 >= hlo) & (cy1 <= hhi) & (cx0 >= wlo) & (cx1 <= whi);
            uint mx;
            if (inH) {
                // byte offset inside one channel-part plane (max 11136 < 2^14)
                const int a00 = ((cy0 - hlo) * HCOLS + (cx0 - wlo)) * 16;
                const int dcb = (cx1 - cx0) << 4;         // 0 or 16
                const int drb = (cy1 - cy0) * HROW_B;     // 0 or 656
                mx = (uint)a00 | ((uint)dcb << 14) | ((uint)drb << 19);
            } else {
                mx = 0x80000000u;                          // sign bit => global fallback
            }
            const uint my = (uint)cy0 | ((uint)cx0 << 8)
                          | ((uint)cy1 << 16) | ((uint)cx1 << 24);

            wts[px_own]   = w4;                 // ds_write_b128
            meta2[px_own] = make_uint2(mx, my); // ds_write_b64
            // same-wave producers/consumers; DS ops from one wave complete in order
        }

        // ---- consumers: 4 M-tiles, params read from LDS ----
        #pragma unroll
        for (int i = 0; i < 4; ++i) {
            const f32x4 w4  = wts[pxc[i]];
            const uint2 mm  = meta2[pxc[i]];

            uint4 q00, q01, q10, q11;
            if ((int)mm.x >= 0) {
                const uint a00 = (mm.x & 0x3fffu) + qb;
                const uint dc  = (mm.x >> 14) & 0x1fu;
                const uint dr  = (mm.x >> 19);
                q00 = *(const uint4*)(hbase + a00);
                q01 = *(const uint4*)(hbase + (a00 + dc));
                q10 = *(const uint4*)(hbase + (a00 + dr));
                q11 = *(const uint4*)(hbase + (a00 + dc + dr));
            } else {
                const int cy0 = mm.y & 255,         cx0 = (mm.y >> 8) & 255;
                const int cy1 = (mm.y >> 16) & 255, cx1 = mm.y >> 24;
                q00 = tfs4[(cy0 * WW + cx0) * 4 + quad];
                q01 = tfs4[(cy0 * WW + cx1) * 4 + quad];
                q10 = tfs4[(cy1 * WW + cx0) * 4 + quad];
                q11 = tfs4[(cy1 * WW + cx1) * 4 + quad];
            }

            U4S8 af;
            af.u.x = blerp_pack(q00.x, q01.x, q10.x, q11.x, w4[0], w4[1], w4[2], w4[3]);
            af.u.y = blerp_pack(q00.y, q01.y, q10.y, q11.y, w4[0], w4[1], w4[2], w4[3]);
            af.u.z = blerp_pack(q00.z, q01.z, q10.z, q11.z, w4[0], w4[1], w4[2], w4[3]);
            af.u.w = blerp_pack(q00.w, q01.w, q10.w, q11.w, w4[0], w4[1], w4[2], w4[3]);

            acc[i][0] = __builtin_amdgcn_mfma_f32_16x16x32_bf16(af.s, bf0.s, acc[i][0], 0, 0, 0);
            acc[i][1] = __builtin_amdgcn_mfma_f32_16x16x32_bf16(af.s, bf1.s, acc[i][1], 0, 0, 0);
        }

        dy = dyn; dx = dxn;
    }

    // ---- epilogue: D[m][n]: n(col)=lane&15 -> o; m(row)=quad*4+r -> pixel ----
    float* ob = out + (size_t)b * COUT * PLANE + (size_t)t * HWSZ;
    #pragma unroll
    for (int i = 0; i < 4; ++i) {
        const int hp    = h0 + 2 * wv + (i >> 1);
        const int wbase = w0 + ((i & 1) << 4) + quad * 4;
        #pragma unroll
        for (int n = 0; n < 2; ++n) {
            const int o = n * 16 + lane15;
            float* op = ob + (size_t)o * PLANE + hp * WW + wbase;
            #pragma unroll
            for (int r = 0; r < 4; ++r) op[r] = acc[i][n][r];
        }
    }
}

// ---------------------------------------------------------------------------
// Round-1 fallback (known-correct) if ws_size is too small.
// ---------------------------------------------------------------------------
__global__ __launch_bounds__(256) void dcn_fp32_kernel(
    const float* __restrict__ feat,
    const float* __restrict__ offset,
    const float* __restrict__ weight,
    float* __restrict__ out)
{
    __shared__ float sw[KK * CIN * COUT];
    const int tid = threadIdx.x;
    const int t   = blockIdx.y;
    const int b   = blockIdx.z;
    {
        const float* wg = weight + (size_t)t * (COUT * CIN * KK);
        #pragma unroll
        for (int j = 0; j < (KK * CIN * COUT) / 256; ++j) {
            int i  = tid + j * 256;
            int k  = i % KK;
            int oc = i / KK;
            sw[(k * CIN + (oc % CIN)) * COUT + (oc / CIN)] = wg[i];
        }
    }
    __syncthreads();

    const int pix = blockIdx.x * 256 + tid;
    const int h   = pix / WW;
    const int w   = pix % WW;

    float acc[COUT];
    #pragma unroll
    for (int o = 0; o < COUT; ++o) acc[o] = 0.0f;

    const float* offp = offset + ((size_t)(b * 2 * KK) * TT + t) * HWSZ + pix;
    float offv[2 * KK];
    #pragma unroll
    for (int j = 0; j < 2 * KK; ++j) offv[j] = offp[(size_t)j * PLANE];

    const float* fbase = feat + ((size_t)(b * CIN) * TT + t) * HWSZ;

    for (int k = 0; k < KK; ++k) {
        const float ys = (float)(h + k / 3 - 1) + offv[2 * k];
        const float xs = (float)(w + k % 3 - 1) + offv[2 * k + 1];
        const float y0f = floorf(ys), x0f = floorf(xs);
        const float wy1 = ys - y0f, wx1 = xs - x0f;
        const float wy0 = 1.0f - wy1, wx0 = 1.0f - wx1;
        const int y0 = (int)y0f, x0 = (int)x0f, y1 = y0 + 1, x1 = x0 + 1;
        const bool vy0 = (y0 >= 0) && (y0 < HH), vy1 = (y1 >= 0) && (y1 < HH);
        const bool vx0 = (x0 >= 0) && (x0 < WW), vx1 = (x1 >= 0) && (x1 < WW);
        const int cy0 = min(max(y0, 0), HH - 1), cy1 = min(max(y1, 0), HH - 1);
        const int cx0 = min(max(x0, 0), WW - 1), cx1 = min(max(x1, 0), WW - 1);
        const float w00 = wy0 * wx0 * ((vy0 && vx0) ? 1.0f : 0.0f);
        const float w01 = wy0 * wx1 * ((vy0 && vx1) ? 1.0f : 0.0f);
        const float w10 = wy1 * wx0 * ((vy1 && vx0) ? 1.0f : 0.0f);
        const float w11 = wy1 * wx1 * ((vy1 && vx1) ? 1.0f : 0.0f);
        const int i00 = cy0 * WW + cx0, i01 = cy0 * WW + cx1;
        const int i10 = cy1 * WW + cx0, i11 = cy1 * WW + cx1;

        const float*  sp   = fbase;
        const float4* wrow = (const float4*)&sw[k * CIN * COUT];
        for (int c = 0; c < CIN; ++c) {
            const float v = w00 * sp[i00] + w01 * sp[i01]
                          + w10 * sp[i10] + w11 * sp[i11];
            const float4* wp = wrow + c * (COUT / 4);
            #pragma unroll
            for (int o4 = 0; o4 < COUT / 4; ++o4) {
                const float4 wv = wp[o4];
                acc[4 * o4 + 0] += v * wv.x;
                acc[4 * o4 + 1] += v * wv.y;
                acc[4 * o4 + 2] += v * wv.z;
                acc[4 * o4 + 3] += v * wv.w;
            }
            sp += PLANE;
        }
    }

    float* op = out + ((size_t)(b * COUT) * TT + t) * HWSZ + pix;
    #pragma unroll
    for (int o = 0; o < COUT; ++o) op[(size_t)o * PLANE] = acc[o];
}

extern "C" void kernel_launch(void* const* d_in, const int* in_sizes, int n_in,
                              void* d_out, int out_size, void* d_ws, size_t ws_size,
                              hipStream_t stream) {
    const float* feat   = (const float*)d_in[0];
    const float* offset = (const float*)d_in[1];
    const float* weight = (const float*)d_in[2];
    float* out = (float*)d_out;

    const size_t tf_bytes = (size_t)2 * TT * HWSZ * CIN * sizeof(ushort);  // 37.75 MB
    const size_t wf_bytes = (size_t)TT * KK * 2 * 64 * 8 * sizeof(ushort); // 147 KB

    if (ws_size >= tf_bytes + wf_bytes) {
        uint*   tf    = (uint*)d_ws;
        ushort* wfrag = (ushort*)((char*)d_ws + tf_bytes);

        transpose_bf16_kernel<<<dim3(HWSZ / 256, TT, 2), dim3(256), 0, stream>>>(feat, tf);
        wprep_kernel<<<dim3((TT * KK * 2 * 64 * 8 + 255) / 256), dim3(256), 0, stream>>>(weight, wfrag);
        dcn_mfma_kernel<<<dim3(WW / TILE_W, HH / TILE_H, 2 * TT), dim3(256), 0, stream>>>(
            tf, offset, wfrag, out);
    } else {
        dcn_fp32_kernel<<<dim3(HWSZ / 256, TT, 2), dim3(256), 0, stream>>>(feat, offset, weight, out);
    }
}

// Round 3
// 239.877 us; speedup vs baseline: 1.0784x; 1.0346x over previous
//
#include <hip/hip_runtime.h>
#include <hip/hip_bf16.h>

// Pseudo-3D DCN: B=2, C=32, T=8, H=W=192, K=9 (3x3, pad 1), groups=deform_groups=T.
// Round 6: recovery from R5 NaN (op_sel on v_pk_*_f32 is not a supported
// broadcast path -> UB). Packed math now via f32x2 VECTOR CODE (no asm):
// clang's gfx950 ISel forms v_pk_mul_f32/v_pk_fma_f32 from v2f32 ops with
// explicitly splatted weight pairs. Also: skip the hi-half mask in bf16
// unpack (junk mantissa bits <= 2^-7 relative, same order as bf16 rounding).
// Keeps R5's verified items: b32 meta, upfront offset preload.

#define CIN   32
#define COUT  32
#define TT    8
#define HH    192
#define WW    192
#define KK    9
#define HWSZ  (HH * WW)        // 36864
#define PLANE (TT * HWSZ)      // 294912

#define TILE_W 32
#define TILE_H 8
#define HALO   4
#define HROWS  (TILE_H + 2 * HALO + 1)   // 17
#define HCOLS  (TILE_W + 2 * HALO + 1)   // 41
#define HPLANE (HROWS * HCOLS)           // 697
#define HPLANE_B (HPLANE * 16)           // 11152 bytes per channel-part plane
#define HROW_B  (HCOLS * 16)             // 656 bytes per halo row

typedef __attribute__((ext_vector_type(8))) short short8;
typedef __attribute__((ext_vector_type(4))) float f32x4;
typedef __attribute__((ext_vector_type(2))) float f32x2;

union U4S8 { uint4 u; short8 s; };

__device__ __forceinline__ uint pk_bf16(float lo, float hi) {
    float2 p; p.x = lo; p.y = hi;
    __hip_bfloat162 b = __float22bfloat162_rn(p);
    union { __hip_bfloat162 b; uint u; } cv; cv.b = b;
    return cv.u;
}

// unpack 2 bf16 channels -> f32 pair. Hi half keeps the low bf16 as mantissa
// junk (<= 2^-7 relative == bf16 ulp order) -- saves the AND.
__device__ __forceinline__ f32x2 up2(uint u) {
    f32x2 r;
    r.x = __uint_as_float(u << 16);
    r.y = __uint_as_float(u);
    return r;
}

// bilinear-combine one dword (2 channels) from 4 corners; sXX = {wXX, wXX}
__device__ __forceinline__ uint blerp4(uint a, uint b, uint c, uint d,
                                       f32x2 s00, f32x2 s01, f32x2 s10, f32x2 s11) {
    f32x2 r = up2(a) * s00;
    r = up2(b) * s01 + r;   // contracts to v_pk_fma_f32
    r = up2(c) * s10 + r;
    r = up2(d) * s11 + r;
    return pk_bf16(r.x, r.y);
}

// ---------------------------------------------------------------------------
// feat f32 [B,C,T,H,W] -> tf bf16 [B,T,H,W,C] (stored as uint = 2 channels)
// ---------------------------------------------------------------------------
__global__ __launch_bounds__(256) void transpose_bf16_kernel(
    const float* __restrict__ feat, uint* __restrict__ tf)
{
    __shared__ float tile[CIN][257];
    const int p0 = blockIdx.x * 256;
    const int t  = blockIdx.y;
    const int b  = blockIdx.z;

    const float* src = feat + (size_t)b * CIN * PLANE + (size_t)t * HWSZ + p0;
    #pragma unroll
    for (int c = 0; c < CIN; ++c)
        tile[c][threadIdx.x] = src[(size_t)c * PLANE + threadIdx.x];
    __syncthreads();

    uint* dst = tf + ((size_t)(b * TT + t) * HWSZ + p0) * (CIN / 2);
    #pragma unroll
    for (int it = 0; it < 16; ++it) {
        int i  = it * 256 + threadIdx.x;   // 0..4095
        int p  = i >> 4, c2 = i & 15;
        dst[p * 16 + c2] = pk_bf16(tile[2 * c2][p], tile[2 * c2 + 1][p]);
    }
}

// ---------------------------------------------------------------------------
// weight f32 [T][o=32][c=32][k=9] -> wfrag bf16 [t][k][n][lane][j]
//   B-frag element: B[k_dim = (lane>>4)*8 + j][n = ntile*16 + (lane&15)]
// ---------------------------------------------------------------------------
__global__ __launch_bounds__(256) void wprep_kernel(
    const float* __restrict__ wt, ushort* __restrict__ wfrag)
{
    int idx = blockIdx.x * 256 + threadIdx.x;
    if (idx >= TT * KK * 2 * 64 * 8) return;
    int t  = idx / (KK * 1024);
    int f  = idx % (KK * 1024);
    int k  = f >> 10;
    int r2 = f & 1023;
    int n    = r2 >> 9;
    int lane = (r2 >> 3) & 63;
    int j    = r2 & 7;
    int o = n * 16 + (lane & 15);
    int c = (lane >> 4) * 8 + j;
    float v = wt[(((size_t)t * COUT + o) * CIN + c) * KK + k];
    __hip_bfloat16 hb = __float2bfloat16(v);
    union { __hip_bfloat16 b; ushort u; } cv; cv.b = hb;
    wfrag[idx] = cv.u;
}

// ---------------------------------------------------------------------------
// Main MFMA kernel. Block 256 thr = 4 waves. Tile 32x8 pixels.
// Wave wv owns rows h0+2wv, h0+2wv+1; 4 M-tiles of 16 pixels each.
// ---------------------------------------------------------------------------
__global__ __launch_bounds__(256, 3) void dcn_mfma_kernel(
    const uint* __restrict__ tf,        // bf16 channels-last [bt][pix][c/2]
    const float* __restrict__ offset,
    const ushort* __restrict__ wfrag,
    float* __restrict__ out)
{
    __shared__ uint4 halo4[4 * HPLANE];   // plane-major, 44608 B
    __shared__ f32x4 wts[256];            // 4096 B  (per-tap bilinear weights)
    __shared__ uint  meta1[256];          // 1024 B  (packed addr / fallback coords)

    const int tid  = threadIdx.x;
    const int lane = tid & 63;
    const int wv   = tid >> 6;
    const int lane15 = lane & 15;
    const int quad   = lane >> 4;

    const int w0 = blockIdx.x * TILE_W;
    const int h0 = blockIdx.y * TILE_H;
    const int bt = blockIdx.z;
    const int t  = bt & (TT - 1);
    const int b  = bt >> 3;

    const int hlo = h0 - HALO, wlo = w0 - HALO;
    const int hhi = hlo + (HROWS - 1), whi = wlo + (HCOLS - 1);

    const uint4* tfs4 = (const uint4*)tf + (size_t)bt * HWSZ * 4;  // 4 uint4/pixel

    // ---- own pixel (producer role): lane owns one of the wave's 64 pixels ----
    const int prow = h0 + 2 * wv + (lane >> 5);
    const int pcol = w0 + (lane & 31);
    const int px_own = (2 * wv + (lane >> 5)) * 32 + (lane & 31);
    const float* offp = offset + (size_t)b * 2 * KK * PLANE + (size_t)t * HWSZ
                      + prow * WW + pcol;

    // ---- all 18 offset loads issued first: HBM latency hides under staging ----
    float offv[2 * KK];
    #pragma unroll
    for (int j = 0; j < 2 * KK; ++j) offv[j] = offp[(size_t)j * PLANE];

    // ---- stage halo (edge-replicated) into LDS, plane-major ----
    #pragma unroll
    for (int it = 0; it < 11; ++it) {
        int idx = it * 256 + tid;
        if (idx < 4 * HPLANE) {
            int r    = idx / (HCOLS * 4);
            int rem  = idx - r * (HCOLS * 4);
            int pv   = rem >> 2;
            int part = rem & 3;
            int gy = min(max(hlo + r, 0), HH - 1);
            int gx = min(max(wlo + pv, 0), WW - 1);
            halo4[part * HPLANE + r * HCOLS + pv] = tfs4[(gy * WW + gx) * 4 + part];
        }
    }

    const uint4* wfp = (const uint4*)(wfrag + (size_t)t * KK * 2 * 64 * 8);

    f32x4 acc[4][2];
    #pragma unroll
    for (int i = 0; i < 4; ++i)
        #pragma unroll
        for (int n = 0; n < 2; ++n) {
            acc[i][n][0] = 0.f; acc[i][n][1] = 0.f;
            acc[i][n][2] = 0.f; acc[i][n][3] = 0.f;
        }

    // consumer-side param indices (same across taps)
    int pxc[4];
    #pragma unroll
    for (int i = 0; i < 4; ++i)
        pxc[i] = (2 * wv + (i >> 1)) * 32 + ((i & 1) << 4) + lane15;

    const uint qb = (uint)quad * HPLANE_B;
    const char* hbase = (const char*)halo4;

    __syncthreads();

    #pragma unroll
    for (int k = 0; k < KK; ++k) {
        const int ky = k / 3 - 1;
        const int kx = k % 3 - 1;

        // B-fragments for this tap (L1-hot: 9 KB shared by all waves of this t)
        U4S8 bf0, bf1;
        bf0.u = wfp[(k * 2 + 0) * 64 + lane];
        bf1.u = wfp[(k * 2 + 1) * 64 + lane];

        // ---- producer: sampling math ONCE per pixel (shared via wave-private LDS) ----
        {
            const float dy = offv[2 * k];
            const float dx = offv[2 * k + 1];
            const float ys = (float)(prow + ky) + dy;
            const float xs = (float)(pcol + kx) + dx;
            const float y0f = floorf(ys), x0f = floorf(xs);
            const float wy1 = ys - y0f,  wx1 = xs - x0f;
            const float wy0 = 1.f - wy1, wx0 = 1.f - wx1;

            const int y0 = (int)y0f, x0i = (int)x0f;
            const int y1 = y0 + 1,   x1 = x0i + 1;

            const float vy0 = (y0 >= 0 && y0 < HH) ? 1.f : 0.f;
            const float vy1 = (y1 >= 0 && y1 < HH) ? 1.f : 0.f;
            const float vx0 = (x0i >= 0 && x0i < WW) ? 1.f : 0.f;
            const float vx1 = (x1 >= 0 && x1 < WW) ? 1.f : 0.f;

            const int cy0 = min(max(y0, 0), HH - 1);
            const int cy1 = min(max(y1, 0), HH - 1);
            const int cx0 = min(max(x0i, 0), WW - 1);
            const int cx1 = min(max(x1, 0), WW - 1);

            f32x4 w4;
            const float wy0v = wy0 * vy0, wy1v = wy1 * vy1;
            const float wx0v = wx0 * vx0, wx1v = wx1 * vx1;
            w4[0] = wy0v * wx0v;
            w4[1] = wy0v * wx1v;
            w4[2] = wy1v * wx0v;
            w4[3] = wy1v * wx1v;

            const bool inH = (cy0 >= hlo) & (cy1 <= hhi) & (cx0 >= wlo) & (cx1 <= whi);
            uint mx;
            if (inH) {
                // byte offset inside one channel-part plane (max 11136 < 2^14)
                const int a00 = ((cy0 - hlo) * HCOLS + (cx0 - wlo)) * 16;
                const int dcb = (cx1 - cx0) << 4;         // 0 or 16   -> bits 14..18
                const int drb = (cy1 - cy0) * HROW_B;     // 0 or 656  -> bits 19..29
                mx = (uint)a00 | ((uint)dcb << 14) | ((uint)drb << 19);
            } else {
                mx = 0x80000000u | (uint)cy0 | ((uint)cx0 << 8)
                   | ((uint)(cy1 - cy0) << 16) | ((uint)(cx1 - cx0) << 17);
            }

            wts[px_own]   = w4;   // ds_write_b128
            meta1[px_own] = mx;   // ds_write_b32
            // same-wave producers/consumers; DS ops from one wave complete in order
        }

        // ---- consumers: 4 M-tiles, params read from LDS ----
        #pragma unroll
        for (int i = 0; i < 4; ++i) {
            const f32x4 w4 = wts[pxc[i]];
            const uint  mm = meta1[pxc[i]];
            f32x2 s00; s00.x = w4[0]; s00.y = w4[0];
            f32x2 s01; s01.x = w4[1]; s01.y = w4[1];
            f32x2 s10; s10.x = w4[2]; s10.y = w4[2];
            f32x2 s11; s11.x = w4[3]; s11.y = w4[3];

            uint4 q00, q01, q10, q11;
            if ((int)mm >= 0) {
                const uint a00 = (mm & 0x3fffu) + qb;
                const uint dc  = (mm >> 14) & 0x1fu;
                const uint dr  = mm >> 19;
                q00 = *(const uint4*)(hbase + a00);
                q01 = *(const uint4*)(hbase + (a00 + dc));
                q10 = *(const uint4*)(hbase + (a00 + dr));
                q11 = *(const uint4*)(hbase + (a00 + dc + dr));
            } else {
                const int cy0 = mm & 255,        cx0 = (mm >> 8) & 255;
                const int cy1 = cy0 + ((mm >> 16) & 1);
                const int cx1 = cx0 + ((mm >> 17) & 1);
                q00 = tfs4[(cy0 * WW + cx0) * 4 + quad];
                q01 = tfs4[(cy0 * WW + cx1) * 4 + quad];
                q10 = tfs4[(cy1 * WW + cx0) * 4 + quad];
                q11 = tfs4[(cy1 * WW + cx1) * 4 + quad];
            }

            U4S8 af;
            af.u.x = blerp4(q00.x, q01.x, q10.x, q11.x, s00, s01, s10, s11);
            af.u.y = blerp4(q00.y, q01.y, q10.y, q11.y, s00, s01, s10, s11);
            af.u.z = blerp4(q00.z, q01.z, q10.z, q11.z, s00, s01, s10, s11);
            af.u.w = blerp4(q00.w, q01.w, q10.w, q11.w, s00, s01, s10, s11);

            acc[i][0] = __builtin_amdgcn_mfma_f32_16x16x32_bf16(af.s, bf0.s, acc[i][0], 0, 0, 0);
            acc[i][1] = __builtin_amdgcn_mfma_f32_16x16x32_bf16(af.s, bf1.s, acc[i][1], 0, 0, 0);
        }
    }

    // ---- epilogue: D[m][n]: n(col)=lane&15 -> o; m(row)=quad*4+r -> pixel ----
    float* ob = out + (size_t)b * COUT * PLANE + (size_t)t * HWSZ;
    #pragma unroll
    for (int i = 0; i < 4; ++i) {
        const int hp    = h0 + 2 * wv + (i >> 1);
        const int wbase = w0 + ((i & 1) << 4) + quad * 4;
        #pragma unroll
        for (int n = 0; n < 2; ++n) {
            const int o = n * 16 + lane15;
            float* op = ob + (size_t)o * PLANE + hp * WW + wbase;
            #pragma unroll
            for (int r = 0; r < 4; ++r) op[r] = acc[i][n][r];
        }
    }
}

// ---------------------------------------------------------------------------
// Round-1 fallback (known-correct) if ws_size is too small.
// ---------------------------------------------------------------------------
__global__ __launch_bounds__(256) void dcn_fp32_kernel(
    const float* __restrict__ feat,
    const float* __restrict__ offset,
    const float* __restrict__ weight,
    float* __restrict__ out)
{
    __shared__ float sw[KK * CIN * COUT];
    const int tid = threadIdx.x;
    const int t   = blockIdx.y;
    const int b   = blockIdx.z;
    {
        const float* wg = weight + (size_t)t * (COUT * CIN * KK);
        #pragma unroll
        for (int j = 0; j < (KK * CIN * COUT) / 256; ++j) {
            int i  = tid + j * 256;
            int k  = i % KK;
            int oc = i / KK;
            sw[(k * CIN + (oc % CIN)) * COUT + (oc / CIN)] = wg[i];
        }
    }
    __syncthreads();

    const int pix = blockIdx.x * 256 + tid;
    const int h   = pix / WW;
    const int w   = pix % WW;

    float acc[COUT];
    #pragma unroll
    for (int o = 0; o < COUT; ++o) acc[o] = 0.0f;

    const float* offp = offset + ((size_t)(b * 2 * KK) * TT + t) * HWSZ + pix;
    float offv[2 * KK];
    #pragma unroll
    for (int j = 0; j < 2 * KK; ++j) offv[j] = offp[(size_t)j * PLANE];

    const float* fbase = feat + ((size_t)(b * CIN) * TT + t) * HWSZ;

    for (int k = 0; k < KK; ++k) {
        const float ys = (float)(h + k / 3 - 1) + offv[2 * k];
        const float xs = (float)(w + k % 3 - 1) + offv[2 * k + 1];
        const float y0f = floorf(ys), x0f = floorf(xs);
        const float wy1 = ys - y0f, wx1 = xs - x0f;
        const float wy0 = 1.0f - wy1, wx0 = 1.0f - wx1;
        const int y0 = (int)y0f, x0 = (int)x0f, y1 = y0 + 1, x1 = x0 + 1;
        const bool vy0 = (y0 >= 0) && (y0 < HH), vy1 = (y1 >= 0) && (y1 < HH);
        const bool vx0 = (x0 >= 0) && (x0 < WW), vx1 = (x1 >= 0) && (x1 < WW);
        const int cy0 = min(max(y0, 0), HH - 1), cy1 = min(max(y1, 0), HH - 1);
        const int cx0 = min(max(x0, 0), WW - 1), cx1 = min(max(x1, 0), WW - 1);
        const float w00 = wy0 * wx0 * ((vy0 && vx0) ? 1.0f : 0.0f);
        const float w01 = wy0 * wx1 * ((vy0 && vx1) ? 1.0f : 0.0f);
        const float w10 = wy1 * wx0 * ((vy1 && vx0) ? 1.0f : 0.0f);
        const float w11 = wy1 * wx1 * ((vy1 && vx1) ? 1.0f : 0.0f);
        const int i00 = cy0 * WW + cx0, i01 = cy0 * WW + cx1;
        const int i10 = cy1 * WW + cx0, i11 = cy1 * WW + cx1;

        const float*  sp   = fbase;
        const float4* wrow = (const float4*)&sw[k * CIN * COUT];
        for (int c = 0; c < CIN; ++c) {
            const float v = w00 * sp[i00] + w01 * sp[i01]
                          + w10 * sp[i10] + w11 * sp[i11];
            const float4* wp = wrow + c * (COUT / 4);
            #pragma unroll
            for (int o4 = 0; o4 < COUT / 4; ++o4) {
                const float4 wv = wp[o4];
                acc[4 * o4 + 0] += v * wv.x;
                acc[4 * o4 + 1] += v * wv.y;
                acc[4 * o4 + 2] += v * wv.z;
                acc[4 * o4 + 3] += v * wv.w;
            }
            sp += PLANE;
        }
    }

    float* op = out + ((size_t)(b * COUT) * TT + t) * HWSZ + pix;
    #pragma unroll
    for (int o = 0; o < COUT; ++o) op[(size_t)o * PLANE] = acc[o];
}

extern "C" void kernel_launch(void* const* d_in, const int* in_sizes, int n_in,
                              void* d_out, int out_size, void* d_ws, size_t ws_size,
                              hipStream_t stream) {
    const float* feat   = (const float*)d_in[0];
    const float* offset = (const float*)d_in[1];
    const float* weight = (const float*)d_in[2];
    float* out = (float*)d_out;

    const size_t tf_bytes = (size_t)2 * TT * HWSZ * CIN * sizeof(ushort);  // 37.75 MB
    const size_t wf_bytes = (size_t)TT * KK * 2 * 64 * 8 * sizeof(ushort); // 147 KB

    if (ws_size >= tf_bytes + wf_bytes) {
        uint*   tf    = (uint*)d_ws;
        ushort* wfrag = (ushort*)((char*)d_ws + tf_bytes);

        transpose_bf16_kernel<<<dim3(HWSZ / 256, TT, 2), dim3(256), 0, stream>>>(feat, tf);
        wprep_kernel<<<dim3((TT * KK * 2 * 64 * 8 + 255) / 256), dim3(256), 0, stream>>>(weight, wfrag);
        dcn_mfma_kernel<<<dim3(WW / TILE_W, HH / TILE_H, 2 * TT), dim3(256), 0, stream>>>(
            tf, offset, wfrag, out);
    } else {
        dcn_fp32_kernel<<<dim3(HWSZ / 256, TT, 2), dim3(256), 0, stream>>>(feat, offset, weight, out);
    }
}